// Round 13
// baseline (475.233 us; speedup 1.0000x reference)
//
#include <hip/hip_runtime.h>

#define F1 62400
#define O1 800
#define O2N 100
#define TT 300
#define BB 2
#define NWRD 975        /* 64-bit f-words */
#define KSRM 77
#define KREF 11
#define MB 25           /* M-blocks of 32 o */
#define NPAD 640        /* n = b*320 + t */
#define NDIG 4          /* base-256 digits of rint(w1 * 2^31) — exact (R4-proven) */
#define KSPL 10         /* k-splits */
#define WPS 98          /* words per split (last split: 93) */
#define ASTRIDE ((size_t)MB * NDIG * 2048)
#define BSTRIDE ((size_t)NPAD * 4)

typedef unsigned long long u64;
typedef int i32x4 __attribute__((ext_vector_type(4)));

/* ---- ws layout (bytes); NEED ~218.8 MB (ws >= 224.5 MB proven R1; ~798 MB per fill) ---- */
#define OFF_CONST 0ull
#define OFF_Z1I  1024ull
#define OFF_S1T  (OFF_Z1I + 4096000ull)
#define OFF_XBW  (OFF_S1T + 1920000ull)          /* 975*640*8 (320-stride, padded) */
#define OFF_Z1F  (OFF_XBW + 4992000ull)
#define OFF_U1   (OFF_Z1F + 3840000ull)
#define OFF_U2   (OFF_U1 + 3840000ull)
#define OFF_AQ   (OFF_U2 + 480000ull)            /* 975*25*4*2048 = 199,680,000 */
#define NEED_SPARSE (OFF_AQ + 199680000ull)      /* 218,849,024 */

/* K0: SRM/REF kernels, fp64 rounded through fp32 (matches np.float32). */
__global__ void k0_init(double* c) {
    int k = threadIdx.x;
    if (k < KSRM) {
        double v = ((double)k / 10.0) * exp(1.0 - (double)k / 10.0);
        c[k] = (double)(float)v;
    }
    if (k < KREF) {
        double v = -20.0 * (double)k * exp(1.0 - (double)k);
        c[80 + k] = (double)(float)v;
    }
}

/* K1: bitmask xbw[w][b*320+t] (NPAD stride; pad words pre-zeroed by memset):
   bit j = (x[b][w*64+j][t] > 0.5). */
__global__ __launch_bounds__(256) void k1_xbw(const float* __restrict__ x,
                                              u64* __restrict__ xbw) {
    const int NTG = 5;
    int gw = (blockIdx.x * 256 + threadIdx.x) >> 6;
    int lane = threadIdx.x & 63;
    if (gw >= BB * NWRD * NTG) return;
    int b  = gw / (NWRD * NTG);
    int r  = gw % (NWRD * NTG);
    int fw = r / NTG;
    int tg = r % NTG;
    int t = tg * 64 + lane;
    bool act = (t < TT);
    int tc = act ? t : 0;
    const float* xp = x + ((size_t)(b * F1 + (fw << 6))) * TT + tc;
    unsigned lo = 0, hi = 0;
    #pragma unroll
    for (int j = 0; j < 32; ++j)
        lo |= (xp[(size_t)j * TT] > 0.5f ? 1u : 0u) << j;
    #pragma unroll
    for (int j = 0; j < 32; ++j)
        hi |= (xp[(size_t)(j + 32) * TT] > 0.5f ? 1u : 0u) << j;
    if (act)
        xbw[(size_t)fw * NPAD + b * 320 + t] = ((u64)hi << 32) | lo;
}

/* K_QA: quantize all w1 words -> 4 signed base-256 digit planes (scale 2^31,
   exact) in A-fragment order: aq[w][m][dig][o*64 + k]. */
__global__ __launch_bounds__(256) void k_qa(const float* __restrict__ w1,
                                            char* __restrict__ aq) {
    int tid = blockIdx.x * 256 + threadIdx.x;
    if (tid >= NWRD * 3200) return;
    int kc = tid & 3;
    int o  = (tid >> 2) & 31;
    int m  = (tid >> 7) % MB;
    int wl = tid / 3200;
    const float* src = w1 + (size_t)(m * 32 + o) * F1 + (size_t)wl * 64 + kc * 16;
    unsigned dw[NDIG][4];
    #pragma unroll
    for (int g = 0; g < 4; ++g) {
        float4 f4 = *(const float4*)(src + g * 4);
        float ff[4] = {f4.x, f4.y, f4.z, f4.w};
        unsigned w0 = 0, w1_ = 0, w2 = 0, w3 = 0;
        #pragma unroll
        for (int e = 0; e < 4; ++e) {
            int v = (int)rint((double)ff[e] * 2147483648.0);   /* 2^31, exact */
            int d0 = (v << 24) >> 24;  int v1 = (v - d0) >> 8;
            int d1 = (v1 << 24) >> 24; int v2 = (v1 - d1) >> 8;
            int d2 = (v2 << 24) >> 24; int d3 = (v2 - d2) >> 8;
            w0 |= (unsigned)(d0 & 0xFF) << (8 * e);
            w1_ |= (unsigned)(d1 & 0xFF) << (8 * e);
            w2 |= (unsigned)(d2 & 0xFF) << (8 * e);
            w3 |= (unsigned)(d3 & 0xFF) << (8 * e);
        }
        dw[0][g] = w0; dw[1][g] = w1_; dw[2][g] = w2; dw[3][g] = w3;
    }
    char* dst = aq + (((size_t)wl * MB + m) * NDIG) * 2048 + o * 64 + kc * 16;
    #pragma unroll
    for (int d = 0; d < NDIG; ++d)
        *(i32x4*)(dst + (size_t)d * 2048) =
            (i32x4){(int)dw[d][0], (int)dw[d][1], (int)dw[d][2], (int)dw[d][3]};
}

/* LUT-based unpack: 2 ds_read_b64 replace 16 VALU; byte j of lut[v] = bit j
   (identical bytes to the R4-verified mul-trick order). */
#define K3_COMPUTE(A0, A1, A2, A3, BV, TTI)                                        \
    {                                                                              \
        u64 lo_ = lut[(BV) & 0xFFu];                                               \
        u64 hi_ = lut[((BV) >> 8) & 0xFFu];                                        \
        i32x4 bf;                                                                  \
        bf[0] = (int)(unsigned)lo_; bf[1] = (int)(unsigned)(lo_ >> 32);            \
        bf[2] = (int)(unsigned)hi_; bf[3] = (int)(unsigned)(hi_ >> 32);            \
        acc[TTI][0] = __builtin_amdgcn_mfma_i32_16x16x64_i8(A0, bf, acc[TTI][0], 0, 0, 0); \
        acc[TTI][1] = __builtin_amdgcn_mfma_i32_16x16x64_i8(A1, bf, acc[TTI][1], 0, 0, 0); \
        acc[TTI][2] = __builtin_amdgcn_mfma_i32_16x16x64_i8(A2, bf, acc[TTI][2], 0, 0, 0); \
        acc[TTI][3] = __builtin_amdgcn_mfma_i32_16x16x64_i8(A3, bf, acc[TTI][3], 0, 0, 0); \
    }

/* K3M2: exact i8 MFMA GEMM, depth-2 register pipeline + LDS byte-LUT B-unpack.
   ~5% bit density -> most lookups hit lut[0] (same-address broadcast, free). */
__global__ __launch_bounds__(512, 2) void k3m2(const char* __restrict__ aq,
                                               const u64* __restrict__ xbw,
                                               u64* __restrict__ z1i) {
    __shared__ u64 lut[256];
    {
        int i = threadIdx.x;
        if (i < 256) {
            u64 r = 0;
            #pragma unroll
            for (int j = 0; j < 8; ++j)
                r |= (u64)((i >> j) & 1) << (8 * j);
            lut[i] = r;
        }
    }
    __syncthreads();

    int m = blockIdx.x >> 1, nh = blockIdx.x & 1, ksl = blockIdx.y;
    int tid = threadIdx.x;
    int l = tid & 63, wid = tid >> 6;
    int q = wid & 3, oh = wid >> 2;

    int wl0 = ksl * WPS;
    int wend = wl0 + WPS; if (wend > NWRD) wend = NWRD;
    int steps = wend - wl0;           /* 98 or 93 */

    i32x4 acc[5][NDIG];
    #pragma unroll
    for (int i = 0; i < 5; ++i)
        #pragma unroll
        for (int d = 0; d < NDIG; ++d) acc[i][d] = (i32x4){0, 0, 0, 0};

    const char* ap0 = aq + (((size_t)wl0 * MB + m) * NDIG) * 2048
                      + oh * 1024 + (l & 15) * 64 + (l >> 4) * 16;
    const unsigned short* bp0 =
        (const unsigned short*)((const char*)xbw
            + ((size_t)wl0 * NPAD
               + (size_t)(nh * 320 + q * 80 + (l & 15))) * 8
            + (l >> 4) * 2);

    /* prologue: step 0 -> cur (a/b), step 1 -> nxt (c/d) */
    i32x4 a0 = *(const i32x4*)(ap0);
    i32x4 a1 = *(const i32x4*)(ap0 + 2048);
    i32x4 a2 = *(const i32x4*)(ap0 + 4096);
    i32x4 a3 = *(const i32x4*)(ap0 + 6144);
    unsigned b0 = bp0[0], b1 = bp0[64], b2 = bp0[128], b3 = bp0[192], b4 = bp0[256];

    const char* ap1 = ap0 + ASTRIDE;
    const unsigned short* bp1 = bp0 + BSTRIDE;
    i32x4 c0 = *(const i32x4*)(ap1);
    i32x4 c1 = *(const i32x4*)(ap1 + 2048);
    i32x4 c2 = *(const i32x4*)(ap1 + 4096);
    i32x4 c3 = *(const i32x4*)(ap1 + 6144);
    unsigned d0 = bp1[0], d1 = bp1[64], d2 = bp1[128], d3 = bp1[192], d4 = bp1[256];

    #pragma unroll 2
    for (int s = 0; s < steps; ++s) {
        int pf = s + 2; if (pf >= steps) pf = steps - 1;
        const char* app = ap0 + (size_t)pf * ASTRIDE;
        const unsigned short* bpp = bp0 + (size_t)pf * BSTRIDE;
        /* issue prefetch for step s+2 */
        i32x4 p0 = *(const i32x4*)(app);
        i32x4 p1 = *(const i32x4*)(app + 2048);
        i32x4 p2 = *(const i32x4*)(app + 4096);
        i32x4 p3 = *(const i32x4*)(app + 6144);
        unsigned e0 = bpp[0], e1 = bpp[64], e2 = bpp[128], e3 = bpp[192], e4 = bpp[256];
        /* compute step s from cur (B via LDS LUT) */
        K3_COMPUTE(a0, a1, a2, a3, b0, 0)
        K3_COMPUTE(a0, a1, a2, a3, b1, 1)
        K3_COMPUTE(a0, a1, a2, a3, b2, 2)
        K3_COMPUTE(a0, a1, a2, a3, b3, 3)
        K3_COMPUTE(a0, a1, a2, a3, b4, 4)
        /* rotate: cur <- nxt <- prefetched */
        a0 = c0; a1 = c1; a2 = c2; a3 = c3;
        b0 = d0; b1 = d1; b2 = d2; b3 = d3; b4 = d4;
        c0 = p0; c1 = p1; c2 = p2; c3 = p3;
        d0 = e0; d1 = e1; d2 = e2; d3 = e3; d4 = e4;
    }

    #pragma unroll
    for (int tt = 0; tt < 5; ++tt) {
        int n = nh * 320 + q * 80 + tt * 16 + (l & 15);
        #pragma unroll
        for (int r = 0; r < 4; ++r) {
            int o = oh * 16 + (l >> 4) * 4 + r;
            long long c = (long long)acc[tt][0][r]
                        + ((long long)acc[tt][1][r] << 8)
                        + ((long long)acc[tt][2][r] << 16)
                        + ((long long)acc[tt][3][r] << 24);
            atomicAdd(&z1i[(size_t)(m * 32 + o) * NPAD + n], (u64)c);
        }
    }
}

/* dense fallback GEMM1 (used only if ws too small) -> z1f fp64 */
__global__ __launch_bounds__(256) void k_dense_gemm1(const float* __restrict__ x,
                                                     const float* __restrict__ w1,
                                                     double* __restrict__ z1) {
    int lin = blockIdx.x;
    int ot = lin % 25; int tt = (lin / 25) % 5; int b = lin / 125;
    int t0 = tt * 64, o0 = ot * 32;
    __shared__ float xs[64][64];
    __shared__ float wsh[32][64];
    int ti = threadIdx.x & 63, og = threadIdx.x >> 6;
    double dacc[8] = {0, 0, 0, 0, 0, 0, 0, 0};
    for (int fc = 0; fc < F1; fc += 64) {
        __syncthreads();
        for (int e = threadIdx.x; e < 64 * 64; e += 256) {
            int r = e >> 6, c = e & 63;
            int t = t0 + c;
            xs[r][c] = (t < TT) ? x[((size_t)b * F1 + fc + r) * TT + t] : 0.0f;
        }
        for (int e = threadIdx.x; e < 32 * 64; e += 256) {
            int r = e >> 6, c = e & 63;
            wsh[r][c] = w1[(size_t)(o0 + r) * F1 + fc + c];
        }
        __syncthreads();
        float facc[8] = {0, 0, 0, 0, 0, 0, 0, 0};
        for (int ff = 0; ff < 64; ++ff) {
            float xv = xs[ff][ti];
            #pragma unroll
            for (int oo = 0; oo < 8; ++oo) facc[oo] += wsh[og * 8 + oo][ff] * xv;
        }
        #pragma unroll
        for (int oo = 0; oo < 8; ++oo) dacc[oo] += (double)facc[oo];
    }
    int t = t0 + ti;
    if (t < TT) {
        #pragma unroll
        for (int oo = 0; oo < 8; ++oo) {
            int o = o0 + og * 8 + oo;
            z1[((size_t)(b * O1 + o)) * TT + t] = dacc[oo];
        }
    }
}

/* K_CONV1: scale + psp conv for layer 1 (t-parallel, per-row block). */
__global__ __launch_bounds__(320) void k_conv1(const u64* __restrict__ z1i,
                                               const double* __restrict__ z1f,
                                               double* __restrict__ u1,
                                               const double* __restrict__ cst,
                                               int mode) {
    __shared__ double zs[TT];
    __shared__ double ck[KSRM];
    int row = blockIdx.x;                 /* b*800 + o */
    int b = row / O1, o = row % O1;
    int t = threadIdx.x;
    if (t < KSRM) ck[t] = cst[t];
    if (t < TT) {
        double z;
        if (mode == 0)
            z = (double)(long long)z1i[(size_t)o * NPAD + b * 320 + t]
                * 4.656612873077393e-10;                    /* 2^-31 */
        else
            z = z1f[(size_t)row * TT + t];
        zs[t] = z;
    }
    __syncthreads();
    if (t < TT) {
        int kmax = t < (KSRM - 1) ? t : (KSRM - 1);
        double acc = 0.0;
        for (int k = 0; k <= kmax; ++k) acc += ck[k] * zs[t - k];
        u1[(size_t)row * TT + t] = acc;
    }
}

/* K_SCAN: thread-per-row spike scan, branch-free cndmask chains with
   tree-summed refractory term (fp64 reassoc ~1e-14 << spike margin). */
__global__ __launch_bounds__(64) void k_scan(const double* __restrict__ u,
                                             float* __restrict__ s,
                                             const double* __restrict__ cst,
                                             int nrows) {
    int row = blockIdx.x * 64 + threadIdx.x;
    if (row >= nrows) return;
    double rk1 = cst[81], rk2 = cst[82], rk3 = cst[83], rk4 = cst[84];
    double rk5 = cst[85], rk6 = cst[86], rk7 = cst[87], rk8 = cst[88];
    double rk9 = cst[89], rk10 = cst[90];
    const double* ur = u + (size_t)row * TT;
    float* sr = s + (size_t)row * TT;
    unsigned h = 0;
    #pragma unroll 4
    for (int t = 0; t < TT; ++t) {
        double a  = ((h & 1u)   ? rk1 : 0.0) + ((h & 2u)   ? rk2  : 0.0);
        double b2 = ((h & 4u)   ? rk3 : 0.0) + ((h & 8u)   ? rk4  : 0.0);
        double c2 = ((h & 16u)  ? rk5 : 0.0) + ((h & 32u)  ? rk6  : 0.0);
        double d2 = ((h & 64u)  ? rk7 : 0.0) + ((h & 128u) ? rk8  : 0.0);
        double e2 = ((h & 256u) ? rk9 : 0.0) + ((h & 512u) ? rk10 : 0.0);
        double ueff = ur[t] + (((a + b2) + (c2 + d2)) + e2);
        unsigned sp = (ueff >= 10.0) ? 1u : 0u;
        sr[t] = (float)sp;
        h = (h << 1) | sp;
    }
}

/* K_GEMM2C: fused GEMM2 + psp conv for layer 2 (both t-parallel). */
__global__ __launch_bounds__(320) void k_gemm2c(const float* __restrict__ s1t,
                                                const float* __restrict__ w2,
                                                double* __restrict__ u2,
                                                const double* __restrict__ cst) {
    __shared__ float wsm[O1];
    __shared__ double zs[TT];
    __shared__ double ck[KSRM];
    int bo = blockIdx.x;                  /* b*100 + o2 */
    int b = bo / O2N, o2 = bo % O2N;
    int t = threadIdx.x;
    if (t < KSRM) ck[t] = cst[t];
    for (int f = t; f < O1; f += 320) wsm[f] = w2[(size_t)o2 * O1 + f];
    __syncthreads();
    if (t < TT) {
        double acc = 0.0;
        #pragma unroll 4
        for (int f = 0; f < O1; ++f)
            acc += (double)(wsm[f] * s1t[((size_t)(b * O1 + f)) * TT + t]);
        zs[t] = acc;
    }
    __syncthreads();
    if (t < TT) {
        int kmax = t < (KSRM - 1) ? t : (KSRM - 1);
        double acc = 0.0;
        for (int k = 0; k <= kmax; ++k) acc += ck[k] * zs[t - k];
        u2[(size_t)bo * TT + t] = acc;
    }
}

extern "C" void kernel_launch(void* const* d_in, const int* in_sizes, int n_in,
                              void* d_out, int out_size, void* d_ws, size_t ws_size,
                              hipStream_t stream) {
    const float* x  = (const float*)d_in[0];
    const float* w1 = (const float*)d_in[1];
    const float* w2 = (const float*)d_in[2];
    float* out = (float*)d_out;
    char* ws = (char*)d_ws;

    double* cst = (double*)(ws + OFF_CONST);
    u64*    z1i = (u64*)   (ws + OFF_Z1I);
    float*  s1t = (float*) (ws + OFF_S1T);
    u64*    xbw = (u64*)   (ws + OFF_XBW);
    double* z1f = (double*)(ws + OFF_Z1F);
    double* u1  = (double*)(ws + OFF_U1);
    double* u2  = (double*)(ws + OFF_U2);
    char*   aq  = (char*)  (ws + OFF_AQ);

    k0_init<<<1, 128, 0, stream>>>(cst);

    int mode;
    if (ws_size >= NEED_SPARSE) {
        mode = 0;
        hipMemsetAsync(xbw, 0, (size_t)NWRD * NPAD * 8, stream);   /* pad words -> 0 */
        int b1 = (BB * NWRD * 5 * 64 + 255) / 256;
        k1_xbw<<<b1, 256, 0, stream>>>(x, xbw);
        hipMemsetAsync(z1i, 0, (size_t)O1 * NPAD * 8, stream);
        k_qa<<<(NWRD * 3200 + 255) / 256, 256, 0, stream>>>(w1, aq);
        k3m2<<<dim3(2 * MB, KSPL), 512, 0, stream>>>(aq, xbw, z1i);
    } else {
        mode = 1;
        k_dense_gemm1<<<250, 256, 0, stream>>>(x, w1, z1f);
    }

    k_conv1<<<BB * O1, 320, 0, stream>>>(z1i, z1f, u1, cst, mode);
    k_scan<<<(BB * O1 + 63) / 64, 64, 0, stream>>>(u1, s1t, cst, BB * O1);
    k_gemm2c<<<BB * O2N, 320, 0, stream>>>(s1t, w2, u2, cst);
    k_scan<<<(BB * O2N + 63) / 64, 64, 0, stream>>>(u2, out, cst, BB * O2N);
    (void)in_sizes; (void)n_in; (void)out_size;
}

// Round 14
// 465.564 us; speedup vs baseline: 1.0208x; 1.0208x over previous
//
#include <hip/hip_runtime.h>

#define F1 62400
#define O1 800
#define O2N 100
#define TT 300
#define BB 2
#define NWRD 975        /* 64-bit f-words */
#define KSRM 77
#define KREF 11
#define MB 25           /* M-blocks of 32 o */
#define NPAD 640        /* n = b*320 + t */
#define NDIG 4          /* base-256 digits of rint(w1 * 2^31) — exact (R4-proven) */
#define WA 490          /* phase-A words */
#define WB 485          /* phase-B words */
#define KSPL 10         /* k-splits per phase */
#define WPS 49          /* words per split */
#define ASTRIDE ((size_t)MB * NDIG * 2048)
#define BSTRIDE ((size_t)NPAD * 4)

typedef unsigned long long u64;
typedef int i32x4 __attribute__((ext_vector_type(4)));

/* ---- ws layout (bytes); NEED ~119.4 MB ---- */
#define OFF_CONST 0ull
#define OFF_Z1I  1024ull
#define OFF_S1T  (OFF_Z1I + 4096000ull)
#define OFF_XBW  (OFF_S1T + 1920000ull)          /* 975*640*8 (320-stride, pad stored 0) */
#define OFF_Z1F  (OFF_XBW + 4992000ull)
#define OFF_U1   (OFF_Z1F + 3840000ull)
#define OFF_U2   (OFF_U1 + 3840000ull)
#define OFF_AQ   (OFF_U2 + 480000ull)            /* 490*25*4*2048 = 100,352,000 */
#define NEED_SPARSE (OFF_AQ + 100352000ull)      /* ~119.4 MB */

/* K0: SRM/REF kernels, fp64 rounded through fp32 (matches np.float32). */
__global__ void k0_init(double* c) {
    int k = threadIdx.x;
    if (k < KSRM) {
        double v = ((double)k / 10.0) * exp(1.0 - (double)k / 10.0);
        c[k] = (double)(float)v;
    }
    if (k < KREF) {
        double v = -20.0 * (double)k * exp(1.0 - (double)k);
        c[80 + k] = (double)(float)v;
    }
}

/* K1: bitmask xbw[w][b*320+t]: bit j = (x[b][w*64+j][t] > 0.5).
   Pad t in [300,320) stored as 0 (no separate memset needed). */
__global__ __launch_bounds__(256) void k1_xbw(const float* __restrict__ x,
                                              u64* __restrict__ xbw) {
    const int NTG = 5;
    int gw = (blockIdx.x * 256 + threadIdx.x) >> 6;
    int lane = threadIdx.x & 63;
    if (gw >= BB * NWRD * NTG) return;
    int b  = gw / (NWRD * NTG);
    int r  = gw % (NWRD * NTG);
    int fw = r / NTG;
    int tg = r % NTG;
    int t = tg * 64 + lane;          /* always < 320 */
    bool act = (t < TT);
    int tc = act ? t : 0;
    const float* xp = x + ((size_t)(b * F1 + (fw << 6))) * TT + tc;
    unsigned lo = 0, hi = 0;
    #pragma unroll
    for (int j = 0; j < 32; ++j)
        lo |= (xp[(size_t)j * TT] > 0.5f ? 1u : 0u) << j;
    #pragma unroll
    for (int j = 0; j < 32; ++j)
        hi |= (xp[(size_t)(j + 32) * TT] > 0.5f ? 1u : 0u) << j;
    u64 mval = act ? (((u64)hi << 32) | lo) : 0ull;
    xbw[(size_t)fw * NPAD + b * 320 + t] = mval;
}

/* K_QA: quantize w1 words [w_base, w_base+nw) -> 4 signed base-256 digit
   planes (scale 2^31, exact) in A-fragment order: aq[wl][m][dig][o*64+k]. */
__global__ __launch_bounds__(256) void k_qa(const float* __restrict__ w1,
                                            char* __restrict__ aq,
                                            int w_base, int nw) {
    int tid = blockIdx.x * 256 + threadIdx.x;
    if (tid >= nw * 3200) return;
    int kc = tid & 3;
    int o  = (tid >> 2) & 31;
    int m  = (tid >> 7) % MB;
    int wl = tid / 3200;
    const float* src = w1 + (size_t)(m * 32 + o) * F1 + (size_t)(w_base + wl) * 64 + kc * 16;
    unsigned dw[NDIG][4];
    #pragma unroll
    for (int g = 0; g < 4; ++g) {
        float4 f4 = *(const float4*)(src + g * 4);
        float ff[4] = {f4.x, f4.y, f4.z, f4.w};
        unsigned w0 = 0, w1_ = 0, w2 = 0, w3 = 0;
        #pragma unroll
        for (int e = 0; e < 4; ++e) {
            int v = (int)rint((double)ff[e] * 2147483648.0);   /* 2^31, exact */
            int d0 = (v << 24) >> 24;  int v1 = (v - d0) >> 8;
            int d1 = (v1 << 24) >> 24; int v2 = (v1 - d1) >> 8;
            int d2 = (v2 << 24) >> 24; int d3 = (v2 - d2) >> 8;
            w0 |= (unsigned)(d0 & 0xFF) << (8 * e);
            w1_ |= (unsigned)(d1 & 0xFF) << (8 * e);
            w2 |= (unsigned)(d2 & 0xFF) << (8 * e);
            w3 |= (unsigned)(d3 & 0xFF) << (8 * e);
        }
        dw[0][g] = w0; dw[1][g] = w1_; dw[2][g] = w2; dw[3][g] = w3;
    }
    char* dst = aq + (((size_t)wl * MB + m) * NDIG) * 2048 + o * 64 + kc * 16;
    #pragma unroll
    for (int d = 0; d < NDIG; ++d)
        *(i32x4*)(dst + (size_t)d * 2048) =
            (i32x4){(int)dw[d][0], (int)dw[d][1], (int)dw[d][2], (int)dw[d][3]};
}

/* unpack 16 mask bits -> 16 i8 (R4-verified byte order) + 4 digit MFMAs */
#define K3_COMPUTE(A0, A1, A2, A3, BV, TTI)                                        \
    {                                                                              \
        i32x4 bf;                                                                  \
        _Pragma("unroll")                                                          \
        for (int i_ = 0; i_ < 4; ++i_)                                             \
            bf[i_] = (int)((((BV >> (4 * i_)) & 0xFu) * 0x00204081u) & 0x01010101u); \
        acc[TTI][0] = __builtin_amdgcn_mfma_i32_16x16x64_i8(A0, bf, acc[TTI][0], 0, 0, 0); \
        acc[TTI][1] = __builtin_amdgcn_mfma_i32_16x16x64_i8(A1, bf, acc[TTI][1], 0, 0, 0); \
        acc[TTI][2] = __builtin_amdgcn_mfma_i32_16x16x64_i8(A2, bf, acc[TTI][2], 0, 0, 0); \
        acc[TTI][3] = __builtin_amdgcn_mfma_i32_16x16x64_i8(A3, bf, acc[TTI][3], 0, 0, 0); \
    }

/* K3M2: exact i8 MFMA GEMM, depth-2 register pipeline, VALU B-unpack.
   Two-phase host schedule keeps the 100 MB A-slice LLC-resident between
   k_qa (producer) and this kernel (consumer). */
__global__ __launch_bounds__(512, 2) void k3m2(const char* __restrict__ aq,
                                               const u64* __restrict__ xbw,
                                               u64* __restrict__ z1i,
                                               int w_base, int nw) {
    int m = blockIdx.x >> 1, nh = blockIdx.x & 1, ksl = blockIdx.y;
    int tid = threadIdx.x;
    int l = tid & 63, wid = tid >> 6;
    int q = wid & 3, oh = wid >> 2;

    int wl0 = ksl * WPS;
    int wend = wl0 + WPS; if (wend > nw) wend = nw;
    int steps = wend - wl0;
    if (steps <= 0) return;

    i32x4 acc[5][NDIG];
    #pragma unroll
    for (int i = 0; i < 5; ++i)
        #pragma unroll
        for (int d = 0; d < NDIG; ++d) acc[i][d] = (i32x4){0, 0, 0, 0};

    const char* ap0 = aq + (((size_t)wl0 * MB + m) * NDIG) * 2048
                      + oh * 1024 + (l & 15) * 64 + (l >> 4) * 16;
    const unsigned short* bp0 =
        (const unsigned short*)((const char*)xbw
            + ((size_t)(w_base + wl0) * NPAD
               + (size_t)(nh * 320 + q * 80 + (l & 15))) * 8
            + (l >> 4) * 2);

    /* prologue: step 0 -> cur (a/b), step 1 -> nxt (c/d) */
    i32x4 a0 = *(const i32x4*)(ap0);
    i32x4 a1 = *(const i32x4*)(ap0 + 2048);
    i32x4 a2 = *(const i32x4*)(ap0 + 4096);
    i32x4 a3 = *(const i32x4*)(ap0 + 6144);
    unsigned b0 = bp0[0], b1 = bp0[64], b2 = bp0[128], b3 = bp0[192], b4 = bp0[256];

    const char* ap1 = ap0 + ((steps > 1) ? ASTRIDE : 0);
    const unsigned short* bp1 = bp0 + ((steps > 1) ? BSTRIDE : 0);
    i32x4 c0 = *(const i32x4*)(ap1);
    i32x4 c1 = *(const i32x4*)(ap1 + 2048);
    i32x4 c2 = *(const i32x4*)(ap1 + 4096);
    i32x4 c3 = *(const i32x4*)(ap1 + 6144);
    unsigned d0 = bp1[0], d1 = bp1[64], d2 = bp1[128], d3 = bp1[192], d4 = bp1[256];

    #pragma unroll 2
    for (int s = 0; s < steps; ++s) {
        int pf = s + 2; if (pf >= steps) pf = steps - 1;
        const char* app = ap0 + (size_t)pf * ASTRIDE;
        const unsigned short* bpp = bp0 + (size_t)pf * BSTRIDE;
        /* issue prefetch for step s+2 */
        i32x4 p0 = *(const i32x4*)(app);
        i32x4 p1 = *(const i32x4*)(app + 2048);
        i32x4 p2 = *(const i32x4*)(app + 4096);
        i32x4 p3 = *(const i32x4*)(app + 6144);
        unsigned e0 = bpp[0], e1 = bpp[64], e2 = bpp[128], e3 = bpp[192], e4 = bpp[256];
        /* compute step s from cur */
        K3_COMPUTE(a0, a1, a2, a3, b0, 0)
        K3_COMPUTE(a0, a1, a2, a3, b1, 1)
        K3_COMPUTE(a0, a1, a2, a3, b2, 2)
        K3_COMPUTE(a0, a1, a2, a3, b3, 3)
        K3_COMPUTE(a0, a1, a2, a3, b4, 4)
        /* rotate: cur <- nxt <- prefetched */
        a0 = c0; a1 = c1; a2 = c2; a3 = c3;
        b0 = d0; b1 = d1; b2 = d2; b3 = d3; b4 = d4;
        c0 = p0; c1 = p1; c2 = p2; c3 = p3;
        d0 = e0; d1 = e1; d2 = e2; d3 = e3; d4 = e4;
    }

    #pragma unroll
    for (int tt = 0; tt < 5; ++tt) {
        int n = nh * 320 + q * 80 + tt * 16 + (l & 15);
        #pragma unroll
        for (int r = 0; r < 4; ++r) {
            int o = oh * 16 + (l >> 4) * 4 + r;
            long long c = (long long)acc[tt][0][r]
                        + ((long long)acc[tt][1][r] << 8)
                        + ((long long)acc[tt][2][r] << 16)
                        + ((long long)acc[tt][3][r] << 24);
            atomicAdd(&z1i[(size_t)(m * 32 + o) * NPAD + n], (u64)c);
        }
    }
}

/* dense fallback GEMM1 (used only if ws too small) -> z1f fp64 */
__global__ __launch_bounds__(256) void k_dense_gemm1(const float* __restrict__ x,
                                                     const float* __restrict__ w1,
                                                     double* __restrict__ z1) {
    int lin = blockIdx.x;
    int ot = lin % 25; int tt = (lin / 25) % 5; int b = lin / 125;
    int t0 = tt * 64, o0 = ot * 32;
    __shared__ float xs[64][64];
    __shared__ float wsh[32][64];
    int ti = threadIdx.x & 63, og = threadIdx.x >> 6;
    double dacc[8] = {0, 0, 0, 0, 0, 0, 0, 0};
    for (int fc = 0; fc < F1; fc += 64) {
        __syncthreads();
        for (int e = threadIdx.x; e < 64 * 64; e += 256) {
            int r = e >> 6, c = e & 63;
            int t = t0 + c;
            xs[r][c] = (t < TT) ? x[((size_t)b * F1 + fc + r) * TT + t] : 0.0f;
        }
        for (int e = threadIdx.x; e < 32 * 64; e += 256) {
            int r = e >> 6, c = e & 63;
            wsh[r][c] = w1[(size_t)(o0 + r) * F1 + fc + c];
        }
        __syncthreads();
        float facc[8] = {0, 0, 0, 0, 0, 0, 0, 0};
        for (int ff = 0; ff < 64; ++ff) {
            float xv = xs[ff][ti];
            #pragma unroll
            for (int oo = 0; oo < 8; ++oo) facc[oo] += wsh[og * 8 + oo][ff] * xv;
        }
        #pragma unroll
        for (int oo = 0; oo < 8; ++oo) dacc[oo] += (double)facc[oo];
    }
    int t = t0 + ti;
    if (t < TT) {
        #pragma unroll
        for (int oo = 0; oo < 8; ++oo) {
            int o = o0 + og * 8 + oo;
            z1[((size_t)(b * O1 + o)) * TT + t] = dacc[oo];
        }
    }
}

/* K_CONV1: scale + psp conv for layer 1 (t-parallel, per-row block). */
__global__ __launch_bounds__(320) void k_conv1(const u64* __restrict__ z1i,
                                               const double* __restrict__ z1f,
                                               double* __restrict__ u1,
                                               const double* __restrict__ cst,
                                               int mode) {
    __shared__ double zs[TT];
    __shared__ double ck[KSRM];
    int row = blockIdx.x;                 /* b*800 + o */
    int b = row / O1, o = row % O1;
    int t = threadIdx.x;
    if (t < KSRM) ck[t] = cst[t];
    if (t < TT) {
        double z;
        if (mode == 0)
            z = (double)(long long)z1i[(size_t)o * NPAD + b * 320 + t]
                * 4.656612873077393e-10;                    /* 2^-31 */
        else
            z = z1f[(size_t)row * TT + t];
        zs[t] = z;
    }
    __syncthreads();
    if (t < TT) {
        int kmax = t < (KSRM - 1) ? t : (KSRM - 1);
        double acc = 0.0;
        for (int k = 0; k <= kmax; ++k) acc += ck[k] * zs[t - k];
        u1[(size_t)row * TT + t] = acc;
    }
}

/* K_SCAN: thread-per-row spike scan, branch-free cndmask chains with
   tree-summed refractory term (fp64 reassoc ~1e-14 << spike margin). */
__global__ __launch_bounds__(64) void k_scan(const double* __restrict__ u,
                                             float* __restrict__ s,
                                             const double* __restrict__ cst,
                                             int nrows) {
    int row = blockIdx.x * 64 + threadIdx.x;
    if (row >= nrows) return;
    double rk1 = cst[81], rk2 = cst[82], rk3 = cst[83], rk4 = cst[84];
    double rk5 = cst[85], rk6 = cst[86], rk7 = cst[87], rk8 = cst[88];
    double rk9 = cst[89], rk10 = cst[90];
    const double* ur = u + (size_t)row * TT;
    float* sr = s + (size_t)row * TT;
    unsigned h = 0;
    #pragma unroll 4
    for (int t = 0; t < TT; ++t) {
        double a  = ((h & 1u)   ? rk1 : 0.0) + ((h & 2u)   ? rk2  : 0.0);
        double b2 = ((h & 4u)   ? rk3 : 0.0) + ((h & 8u)   ? rk4  : 0.0);
        double c2 = ((h & 16u)  ? rk5 : 0.0) + ((h & 32u)  ? rk6  : 0.0);
        double d2 = ((h & 64u)  ? rk7 : 0.0) + ((h & 128u) ? rk8  : 0.0);
        double e2 = ((h & 256u) ? rk9 : 0.0) + ((h & 512u) ? rk10 : 0.0);
        double ueff = ur[t] + (((a + b2) + (c2 + d2)) + e2);
        unsigned sp = (ueff >= 10.0) ? 1u : 0u;
        sr[t] = (float)sp;
        h = (h << 1) | sp;
    }
}

/* K_GEMM2C: fused GEMM2 + psp conv for layer 2 (both t-parallel). */
__global__ __launch_bounds__(320) void k_gemm2c(const float* __restrict__ s1t,
                                                const float* __restrict__ w2,
                                                double* __restrict__ u2,
                                                const double* __restrict__ cst) {
    __shared__ float wsm[O1];
    __shared__ double zs[TT];
    __shared__ double ck[KSRM];
    int bo = blockIdx.x;                  /* b*100 + o2 */
    int b = bo / O2N, o2 = bo % O2N;
    int t = threadIdx.x;
    if (t < KSRM) ck[t] = cst[t];
    for (int f = t; f < O1; f += 320) wsm[f] = w2[(size_t)o2 * O1 + f];
    __syncthreads();
    if (t < TT) {
        double acc = 0.0;
        #pragma unroll 4
        for (int f = 0; f < O1; ++f)
            acc += (double)(wsm[f] * s1t[((size_t)(b * O1 + f)) * TT + t]);
        zs[t] = acc;
    }
    __syncthreads();
    if (t < TT) {
        int kmax = t < (KSRM - 1) ? t : (KSRM - 1);
        double acc = 0.0;
        for (int k = 0; k <= kmax; ++k) acc += ck[k] * zs[t - k];
        u2[(size_t)bo * TT + t] = acc;
    }
}

extern "C" void kernel_launch(void* const* d_in, const int* in_sizes, int n_in,
                              void* d_out, int out_size, void* d_ws, size_t ws_size,
                              hipStream_t stream) {
    const float* x  = (const float*)d_in[0];
    const float* w1 = (const float*)d_in[1];
    const float* w2 = (const float*)d_in[2];
    float* out = (float*)d_out;
    char* ws = (char*)d_ws;

    double* cst = (double*)(ws + OFF_CONST);
    u64*    z1i = (u64*)   (ws + OFF_Z1I);
    float*  s1t = (float*) (ws + OFF_S1T);
    u64*    xbw = (u64*)   (ws + OFF_XBW);
    double* z1f = (double*)(ws + OFF_Z1F);
    double* u1  = (double*)(ws + OFF_U1);
    double* u2  = (double*)(ws + OFF_U2);
    char*   aq  = (char*)  (ws + OFF_AQ);

    k0_init<<<1, 128, 0, stream>>>(cst);

    int mode;
    if (ws_size >= NEED_SPARSE) {
        mode = 0;
        int b1 = (BB * NWRD * 5 * 64 + 255) / 256;
        k1_xbw<<<b1, 256, 0, stream>>>(x, xbw);
        hipMemsetAsync(z1i, 0, (size_t)O1 * NPAD * 8, stream);
        /* phase A: words 0..489 — aq slice stays LLC-resident for k3m2 */
        k_qa<<<(WA * 3200 + 255) / 256, 256, 0, stream>>>(w1, aq, 0, WA);
        k3m2<<<dim3(2 * MB, KSPL), 512, 0, stream>>>(aq, xbw, z1i, 0, WA);
        /* phase B: words 490..974 (reuses aq buffer) */
        k_qa<<<(WB * 3200 + 255) / 256, 256, 0, stream>>>(w1, aq, WA, WB);
        k3m2<<<dim3(2 * MB, KSPL), 512, 0, stream>>>(aq, xbw, z1i, WA, WB);
    } else {
        mode = 1;
        k_dense_gemm1<<<250, 256, 0, stream>>>(x, w1, z1f);
    }

    k_conv1<<<BB * O1, 320, 0, stream>>>(z1i, z1f, u1, cst, mode);
    k_scan<<<(BB * O1 + 63) / 64, 64, 0, stream>>>(u1, s1t, cst, BB * O1);
    k_gemm2c<<<BB * O2N, 320, 0, stream>>>(s1t, w2, u2, cst);
    k_scan<<<(BB * O2N + 63) / 64, 64, 0, stream>>>(u2, out, cst, BB * O2N);
    (void)in_sizes; (void)n_in; (void)out_size;
}

// Round 15
// 390.329 us; speedup vs baseline: 1.2175x; 1.1927x over previous
//
#include <hip/hip_runtime.h>

#define F1 62400
#define O1 800
#define O2N 100
#define TT 300
#define BB 2
#define NWRD 975        /* 64-bit f-words */
#define KSRM 77
#define KREF 11
#define MB 25           /* M-blocks of 32 o */
#define NPAD 640        /* n = b*320 + t */
#define NDIG 4          /* base-256 digits of rint(w1 * 2^31) — exact (R4-proven) */
#define KSPL 10         /* k-splits */
#define WPS 98          /* words per split (last split: 93) */
#define ASTRIDE ((size_t)MB * NDIG * 2048)
#define BSTRIDE ((size_t)NPAD * 4)

typedef unsigned long long u64;
typedef int i32x4 __attribute__((ext_vector_type(4)));

/* ---- ws layout (bytes); NEED ~218.8 MB (proven available in R10 run) ---- */
#define OFF_CONST 0ull
#define OFF_Z1I  1024ull
#define OFF_S1T  (OFF_Z1I + 4096000ull)
#define OFF_XBW  (OFF_S1T + 1920000ull)          /* 975*640*8 (320-stride, pad stored 0) */
#define OFF_Z1F  (OFF_XBW + 4992000ull)
#define OFF_U1   (OFF_Z1F + 3840000ull)
#define OFF_U2   (OFF_U1 + 3840000ull)
#define OFF_AQ   (OFF_U2 + 480000ull)            /* 975*25*4*2048 = 199,680,000 */
#define NEED_SPARSE (OFF_AQ + 199680000ull)      /* 218,849,024 */

#define GLOAD_LDS16(g, s) __builtin_amdgcn_global_load_lds( \
    (const __attribute__((address_space(1))) unsigned int*)(g), \
    (__attribute__((address_space(3))) unsigned int*)(s), 16, 0, 0)

/* K0: SRM/REF kernels, fp64 rounded through fp32 (matches np.float32). */
__global__ void k0_init(double* c) {
    int k = threadIdx.x;
    if (k < KSRM) {
        double v = ((double)k / 10.0) * exp(1.0 - (double)k / 10.0);
        c[k] = (double)(float)v;
    }
    if (k < KREF) {
        double v = -20.0 * (double)k * exp(1.0 - (double)k);
        c[80 + k] = (double)(float)v;
    }
}

/* K1: bitmask xbw[w][b*320+t]: bit j = (x[b][w*64+j][t] > 0.5).
   Pad t in [300,320) stored as 0. */
__global__ __launch_bounds__(256) void k1_xbw(const float* __restrict__ x,
                                              u64* __restrict__ xbw) {
    const int NTG = 5;
    int gw = (blockIdx.x * 256 + threadIdx.x) >> 6;
    int lane = threadIdx.x & 63;
    if (gw >= BB * NWRD * NTG) return;
    int b  = gw / (NWRD * NTG);
    int r  = gw % (NWRD * NTG);
    int fw = r / NTG;
    int tg = r % NTG;
    int t = tg * 64 + lane;          /* always < 320 */
    bool act = (t < TT);
    int tc = act ? t : 0;
    const float* xp = x + ((size_t)(b * F1 + (fw << 6))) * TT + tc;
    unsigned lo = 0, hi = 0;
    #pragma unroll
    for (int j = 0; j < 32; ++j)
        lo |= (xp[(size_t)j * TT] > 0.5f ? 1u : 0u) << j;
    #pragma unroll
    for (int j = 0; j < 32; ++j)
        hi |= (xp[(size_t)(j + 32) * TT] > 0.5f ? 1u : 0u) << j;
    u64 mval = act ? (((u64)hi << 32) | lo) : 0ull;
    xbw[(size_t)fw * NPAD + b * 320 + t] = mval;
}

/* K_QA: quantize all w1 words -> 4 signed base-256 digit planes (scale 2^31,
   exact) in A-fragment order: aq[w][m][dig][o*64+k]. */
__global__ __launch_bounds__(256) void k_qa(const float* __restrict__ w1,
                                            char* __restrict__ aq) {
    int tid = blockIdx.x * 256 + threadIdx.x;
    if (tid >= NWRD * 3200) return;
    int kc = tid & 3;
    int o  = (tid >> 2) & 31;
    int m  = (tid >> 7) % MB;
    int wl = tid / 3200;
    const float* src = w1 + (size_t)(m * 32 + o) * F1 + (size_t)wl * 64 + kc * 16;
    unsigned dw[NDIG][4];
    #pragma unroll
    for (int g = 0; g < 4; ++g) {
        float4 f4 = *(const float4*)(src + g * 4);
        float ff[4] = {f4.x, f4.y, f4.z, f4.w};
        unsigned w0 = 0, w1_ = 0, w2 = 0, w3 = 0;
        #pragma unroll
        for (int e = 0; e < 4; ++e) {
            int v = (int)rint((double)ff[e] * 2147483648.0);   /* 2^31, exact */
            int d0 = (v << 24) >> 24;  int v1 = (v - d0) >> 8;
            int d1 = (v1 << 24) >> 24; int v2 = (v1 - d1) >> 8;
            int d2 = (v2 << 24) >> 24; int d3 = (v2 - d2) >> 8;
            w0 |= (unsigned)(d0 & 0xFF) << (8 * e);
            w1_ |= (unsigned)(d1 & 0xFF) << (8 * e);
            w2 |= (unsigned)(d2 & 0xFF) << (8 * e);
            w3 |= (unsigned)(d3 & 0xFF) << (8 * e);
        }
        dw[0][g] = w0; dw[1][g] = w1_; dw[2][g] = w2; dw[3][g] = w3;
    }
    char* dst = aq + (((size_t)wl * MB + m) * NDIG) * 2048 + o * 64 + kc * 16;
    #pragma unroll
    for (int d = 0; d < NDIG; ++d)
        *(i32x4*)(dst + (size_t)d * 2048) =
            (i32x4){(int)dw[d][0], (int)dw[d][1], (int)dw[d][2], (int)dw[d][3]};
}

/* unpack 16 mask bits -> 16 i8 (R4-verified byte order) + 4 digit MFMAs */
#define K3_COMPUTE(A0, A1, A2, A3, BV, TTI)                                        \
    {                                                                              \
        i32x4 bf;                                                                  \
        _Pragma("unroll")                                                          \
        for (int i_ = 0; i_ < 4; ++i_)                                             \
            bf[i_] = (int)((((BV >> (4 * i_)) & 0xFu) * 0x00204081u) & 0x01010101u); \
        acc[TTI][0] = __builtin_amdgcn_mfma_i32_16x16x64_i8(A0, bf, acc[TTI][0], 0, 0, 0); \
        acc[TTI][1] = __builtin_amdgcn_mfma_i32_16x16x64_i8(A1, bf, acc[TTI][1], 0, 0, 0); \
        acc[TTI][2] = __builtin_amdgcn_mfma_i32_16x16x64_i8(A2, bf, acc[TTI][2], 0, 0, 0); \
        acc[TTI][3] = __builtin_amdgcn_mfma_i32_16x16x64_i8(A3, bf, acc[TTI][3], 0, 0, 0); \
    }

/* K3M2: exact i8 MFMA GEMM; A staged via global_load_lds double-buffer
   (8 KB/step, linear both sides), B via register depth-1 prefetch.
   One __syncthreads per step drains the DMA (compiler emits vmcnt(0)). */
__global__ __launch_bounds__(512, 4) void k3m2(const char* __restrict__ aq,
                                               const u64* __restrict__ xbw,
                                               u64* __restrict__ z1i) {
    __shared__ __align__(16) char Abuf[2][8192];
    int m = blockIdx.x >> 1, nh = blockIdx.x & 1, ksl = blockIdx.y;
    int tid = threadIdx.x;
    int l = tid & 63, wid = tid >> 6;
    int q = wid & 3, oh = wid >> 2;

    int wl0 = ksl * WPS;
    int wend = wl0 + WPS; if (wend > NWRD) wend = NWRD;
    int steps = wend - wl0;

    i32x4 acc[5][NDIG];
    #pragma unroll
    for (int i = 0; i < 5; ++i)
        #pragma unroll
        for (int d = 0; d < NDIG; ++d) acc[i][d] = (i32x4){0, 0, 0, 0};

    /* A: per-thread 16B slice of the 8 KB step-tile (identity copy to LDS) */
    const char* abase = aq + (((size_t)wl0 * MB + m) * NDIG) * 2048 + (size_t)tid * 16;
    /* B: packed u16 per (n, k-quarter) */
    const unsigned short* bp0 =
        (const unsigned short*)((const char*)xbw
            + ((size_t)wl0 * NPAD
               + (size_t)(nh * 320 + q * 80 + (l & 15))) * 8
            + (l >> 4) * 2);

    /* prologue: stage step 0, load B for step 0 */
    GLOAD_LDS16(abase, &Abuf[0][tid * 16]);
    unsigned b0 = bp0[0], b1 = bp0[64], b2 = bp0[128], b3 = bp0[192], b4 = bp0[256];
    __syncthreads();

    int cur = 0;
    const char* lfrag = &Abuf[0][0] + oh * 1024 + (l & 15) * 64 + (l >> 4) * 16;

    for (int s = 0; s < steps; ++s) {
        /* issue DMA for step s+1 into the other buffer */
        if (s + 1 < steps)
            GLOAD_LDS16(abase + (size_t)(s + 1) * ASTRIDE, &Abuf[cur ^ 1][tid * 16]);
        /* prefetch B for step s+1 (clamped re-read at tail) */
        int sn = (s + 1 < steps) ? (s + 1) : s;
        const unsigned short* bpn = bp0 + (size_t)sn * BSTRIDE;
        unsigned nb0 = bpn[0], nb1 = bpn[64], nb2 = bpn[128], nb3 = bpn[192], nb4 = bpn[256];
        /* A frags from current buffer (contiguous 1KB/wave ds_read_b128) */
        const char* lp = lfrag + (size_t)cur * 8192;
        i32x4 a0 = *(const i32x4*)(lp);
        i32x4 a1 = *(const i32x4*)(lp + 2048);
        i32x4 a2 = *(const i32x4*)(lp + 4096);
        i32x4 a3 = *(const i32x4*)(lp + 6144);
        K3_COMPUTE(a0, a1, a2, a3, b0, 0)
        K3_COMPUTE(a0, a1, a2, a3, b1, 1)
        K3_COMPUTE(a0, a1, a2, a3, b2, 2)
        K3_COMPUTE(a0, a1, a2, a3, b3, 3)
        K3_COMPUTE(a0, a1, a2, a3, b4, 4)
        b0 = nb0; b1 = nb1; b2 = nb2; b3 = nb3; b4 = nb4;
        __syncthreads();     /* drains DMA (vmcnt) + LDS reads before buffer swap */
        cur ^= 1;
    }

    #pragma unroll
    for (int tt = 0; tt < 5; ++tt) {
        int n = nh * 320 + q * 80 + tt * 16 + (l & 15);
        #pragma unroll
        for (int r = 0; r < 4; ++r) {
            int o = oh * 16 + (l >> 4) * 4 + r;
            long long c = (long long)acc[tt][0][r]
                        + ((long long)acc[tt][1][r] << 8)
                        + ((long long)acc[tt][2][r] << 16)
                        + ((long long)acc[tt][3][r] << 24);
            atomicAdd(&z1i[(size_t)(m * 32 + o) * NPAD + n], (u64)c);
        }
    }
}

/* dense fallback GEMM1 (used only if ws too small) -> z1f fp64 */
__global__ __launch_bounds__(256) void k_dense_gemm1(const float* __restrict__ x,
                                                     const float* __restrict__ w1,
                                                     double* __restrict__ z1) {
    int lin = blockIdx.x;
    int ot = lin % 25; int tt = (lin / 25) % 5; int b = lin / 125;
    int t0 = tt * 64, o0 = ot * 32;
    __shared__ float xs[64][64];
    __shared__ float wsh[32][64];
    int ti = threadIdx.x & 63, og = threadIdx.x >> 6;
    double dacc[8] = {0, 0, 0, 0, 0, 0, 0, 0};
    for (int fc = 0; fc < F1; fc += 64) {
        __syncthreads();
        for (int e = threadIdx.x; e < 64 * 64; e += 256) {
            int r = e >> 6, c = e & 63;
            int t = t0 + c;
            xs[r][c] = (t < TT) ? x[((size_t)b * F1 + fc + r) * TT + t] : 0.0f;
        }
        for (int e = threadIdx.x; e < 32 * 64; e += 256) {
            int r = e >> 6, c = e & 63;
            wsh[r][c] = w1[(size_t)(o0 + r) * F1 + fc + c];
        }
        __syncthreads();
        float facc[8] = {0, 0, 0, 0, 0, 0, 0, 0};
        for (int ff = 0; ff < 64; ++ff) {
            float xv = xs[ff][ti];
            #pragma unroll
            for (int oo = 0; oo < 8; ++oo) facc[oo] += wsh[og * 8 + oo][ff] * xv;
        }
        #pragma unroll
        for (int oo = 0; oo < 8; ++oo) dacc[oo] += (double)facc[oo];
    }
    int t = t0 + ti;
    if (t < TT) {
        #pragma unroll
        for (int oo = 0; oo < 8; ++oo) {
            int o = o0 + og * 8 + oo;
            z1[((size_t)(b * O1 + o)) * TT + t] = dacc[oo];
        }
    }
}

/* K_CONV1: scale + psp conv for layer 1 (t-parallel, per-row block). */
__global__ __launch_bounds__(320) void k_conv1(const u64* __restrict__ z1i,
                                               const double* __restrict__ z1f,
                                               double* __restrict__ u1,
                                               const double* __restrict__ cst,
                                               int mode) {
    __shared__ double zs[TT];
    __shared__ double ck[KSRM];
    int row = blockIdx.x;                 /* b*800 + o */
    int b = row / O1, o = row % O1;
    int t = threadIdx.x;
    if (t < KSRM) ck[t] = cst[t];
    if (t < TT) {
        double z;
        if (mode == 0)
            z = (double)(long long)z1i[(size_t)o * NPAD + b * 320 + t]
                * 4.656612873077393e-10;                    /* 2^-31 */
        else
            z = z1f[(size_t)row * TT + t];
        zs[t] = z;
    }
    __syncthreads();
    if (t < TT) {
        int kmax = t < (KSRM - 1) ? t : (KSRM - 1);
        double acc = 0.0;
        for (int k = 0; k <= kmax; ++k) acc += ck[k] * zs[t - k];
        u1[(size_t)row * TT + t] = acc;
    }
}

/* K_SCAN: thread-per-row spike scan, branch-free cndmask chains with
   tree-summed refractory term (fp64 reassoc ~1e-14 << spike margin). */
__global__ __launch_bounds__(64) void k_scan(const double* __restrict__ u,
                                             float* __restrict__ s,
                                             const double* __restrict__ cst,
                                             int nrows) {
    int row = blockIdx.x * 64 + threadIdx.x;
    if (row >= nrows) return;
    double rk1 = cst[81], rk2 = cst[82], rk3 = cst[83], rk4 = cst[84];
    double rk5 = cst[85], rk6 = cst[86], rk7 = cst[87], rk8 = cst[88];
    double rk9 = cst[89], rk10 = cst[90];
    const double* ur = u + (size_t)row * TT;
    float* sr = s + (size_t)row * TT;
    unsigned h = 0;
    #pragma unroll 4
    for (int t = 0; t < TT; ++t) {
        double a  = ((h & 1u)   ? rk1 : 0.0) + ((h & 2u)   ? rk2  : 0.0);
        double b2 = ((h & 4u)   ? rk3 : 0.0) + ((h & 8u)   ? rk4  : 0.0);
        double c2 = ((h & 16u)  ? rk5 : 0.0) + ((h & 32u)  ? rk6  : 0.0);
        double d2 = ((h & 64u)  ? rk7 : 0.0) + ((h & 128u) ? rk8  : 0.0);
        double e2 = ((h & 256u) ? rk9 : 0.0) + ((h & 512u) ? rk10 : 0.0);
        double ueff = ur[t] + (((a + b2) + (c2 + d2)) + e2);
        unsigned sp = (ueff >= 10.0) ? 1u : 0u;
        sr[t] = (float)sp;
        h = (h << 1) | sp;
    }
}

/* K_GEMM2C: fused GEMM2 + psp conv for layer 2 (both t-parallel). */
__global__ __launch_bounds__(320) void k_gemm2c(const float* __restrict__ s1t,
                                                const float* __restrict__ w2,
                                                double* __restrict__ u2,
                                                const double* __restrict__ cst) {
    __shared__ float wsm[O1];
    __shared__ double zs[TT];
    __shared__ double ck[KSRM];
    int bo = blockIdx.x;                  /* b*100 + o2 */
    int b = bo / O2N, o2 = bo % O2N;
    int t = threadIdx.x;
    if (t < KSRM) ck[t] = cst[t];
    for (int f = t; f < O1; f += 320) wsm[f] = w2[(size_t)o2 * O1 + f];
    __syncthreads();
    if (t < TT) {
        double acc = 0.0;
        #pragma unroll 4
        for (int f = 0; f < O1; ++f)
            acc += (double)(wsm[f] * s1t[((size_t)(b * O1 + f)) * TT + t]);
        zs[t] = acc;
    }
    __syncthreads();
    if (t < TT) {
        int kmax = t < (KSRM - 1) ? t : (KSRM - 1);
        double acc = 0.0;
        for (int k = 0; k <= kmax; ++k) acc += ck[k] * zs[t - k];
        u2[(size_t)bo * TT + t] = acc;
    }
}

extern "C" void kernel_launch(void* const* d_in, const int* in_sizes, int n_in,
                              void* d_out, int out_size, void* d_ws, size_t ws_size,
                              hipStream_t stream) {
    const float* x  = (const float*)d_in[0];
    const float* w1 = (const float*)d_in[1];
    const float* w2 = (const float*)d_in[2];
    float* out = (float*)d_out;
    char* ws = (char*)d_ws;

    double* cst = (double*)(ws + OFF_CONST);
    u64*    z1i = (u64*)   (ws + OFF_Z1I);
    float*  s1t = (float*) (ws + OFF_S1T);
    u64*    xbw = (u64*)   (ws + OFF_XBW);
    double* z1f = (double*)(ws + OFF_Z1F);
    double* u1  = (double*)(ws + OFF_U1);
    double* u2  = (double*)(ws + OFF_U2);
    char*   aq  = (char*)  (ws + OFF_AQ);

    k0_init<<<1, 128, 0, stream>>>(cst);

    int mode;
    if (ws_size >= NEED_SPARSE) {
        mode = 0;
        int b1 = (BB * NWRD * 5 * 64 + 255) / 256;
        k1_xbw<<<b1, 256, 0, stream>>>(x, xbw);
        hipMemsetAsync(z1i, 0, (size_t)O1 * NPAD * 8, stream);
        k_qa<<<(NWRD * 3200 + 255) / 256, 256, 0, stream>>>(w1, aq);
        k3m2<<<dim3(2 * MB, KSPL), 512, 0, stream>>>(aq, xbw, z1i);
    } else {
        mode = 1;
        k_dense_gemm1<<<250, 256, 0, stream>>>(x, w1, z1f);
    }

    k_conv1<<<BB * O1, 320, 0, stream>>>(z1i, z1f, u1, cst, mode);
    k_scan<<<(BB * O1 + 63) / 64, 64, 0, stream>>>(u1, s1t, cst, BB * O1);
    k_gemm2c<<<BB * O2N, 320, 0, stream>>>(s1t, w2, u2, cst);
    k_scan<<<(BB * O2N + 63) / 64, 64, 0, stream>>>(u2, out, cst, BB * O2N);
    (void)in_sizes; (void)n_in; (void)out_size;
}